// Round 1
// baseline (733.444 us; speedup 1.0000x reference)
//
#include <hip/hip_runtime.h>

#define N_NODES 50000
#define N0_ 20000
#define N1_ 15000
#define N2_ 15000
#define E_EDGES 800000
#define H_ 128
#define C_ 64

// ---------------- degree / norm / CSR build ----------------

__global__ void deg_kernel(const int* __restrict__ src, const int* __restrict__ dst,
                           float* __restrict__ degO, float* __restrict__ degI,
                           int* __restrict__ counts) {
    int i = blockIdx.x * 256 + threadIdx.x;
    if (i < E_EDGES) {
        atomicAdd(&degO[src[i]], 1.0f);
        atomicAdd(&degI[dst[i]], 1.0f);
        atomicAdd(&counts[dst[i]], 1);
    }
}

__global__ void norm_kernel(float* __restrict__ degO, float* __restrict__ degI) {
    int i = blockIdx.x * 256 + threadIdx.x;
    if (i < N_NODES) {
        degO[i] = rsqrtf(fmaxf(degO[i], 1.0f));
        degI[i] = rsqrtf(fmaxf(degI[i], 1.0f));
    }
}

__global__ void scan_kernel(const int* __restrict__ counts, int* __restrict__ rowptr) {
    __shared__ int sums[256];
    __shared__ int offs[257];
    int tid = threadIdx.x;
    const int chunk = (N_NODES + 255) / 256;
    int start = tid * chunk;
    int end = min(start + chunk, N_NODES);
    int s = 0;
    for (int i = start; i < end; i++) s += counts[i];
    sums[tid] = s;
    __syncthreads();
    if (tid == 0) {
        int acc = 0;
        for (int i = 0; i < 256; i++) { offs[i] = acc; acc += sums[i]; }
        offs[256] = acc;
    }
    __syncthreads();
    int acc = offs[tid];
    for (int i = start; i < end; i++) { rowptr[i] = acc; acc += counts[i]; }
    if (tid == 0) rowptr[N_NODES] = offs[256];
}

__global__ void fill_kernel(const int* __restrict__ src, const int* __restrict__ dst,
                            const int* __restrict__ rowptr, int* __restrict__ cursor,
                            int* __restrict__ col) {
    int i = blockIdx.x * 256 + threadIdx.x;
    if (i < E_EDGES) {
        int d = dst[i];
        int p = atomicAdd(&cursor[d], 1);
        col[rowptr[d] + p] = src[i];
    }
}

// ---------------- aggregation: one block per dst node, 128 channels ----------------
// out[node][c] = nd[node] * sum_e ns[src_e] * h[src_e][c]   (+ bias, relu for EPI==1)

template <int EPI>
__global__ __launch_bounds__(128) void agg_kernel(
    const float* __restrict__ h, const int* __restrict__ rowptr,
    const int* __restrict__ col, const float* __restrict__ ns,
    const float* __restrict__ nd, const float* __restrict__ bias,
    float* __restrict__ out) {
    int node = blockIdx.x;
    int c = threadIdx.x;
    int beg = rowptr[node], end = rowptr[node + 1];
    float acc = 0.f;
    for (int e = beg; e < end; e++) {
        int s = col[e];
        acc = fmaf(ns[s], h[(size_t)s * H_ + c], acc);
    }
    acc *= nd[node];
    if (EPI == 1) acc = fmaxf(acc + bias[c], 0.f);
    out[(size_t)node * H_ + c] = acc;
}

// ---------------- fp32 tiled GEMM: out[M,TN] = A[M,K] @ W[K,TN] + bias ----------------
// Tile 64 rows x TN cols, K-chunks of 64. 256 threads; thread (tx=tid&31, ty=tid>>5)
// owns rows {ty+8i} x cols {tx+32j}.

template <int TN, bool RELU>
__global__ __launch_bounds__(256) void gemm_kernel(
    const float* __restrict__ A, const float* __restrict__ W,
    const float* __restrict__ bias, float* __restrict__ out, int M, int K) {
    constexpr int NJ = TN / 32;
    __shared__ float As[64 * 64];
    __shared__ float Bs[64 * TN];
    int tid = threadIdx.x;
    int tx = tid & 31;
    int ty = tid >> 5;
    int m0 = blockIdx.x * 64;

    float acc[8][NJ];
#pragma unroll
    for (int i = 0; i < 8; i++)
#pragma unroll
        for (int j = 0; j < NJ; j++) acc[i][j] = 0.f;

    for (int k0 = 0; k0 < K; k0 += 64) {
        // stage A tile (64 x 64)
        for (int t = tid; t < 1024; t += 256) {
            int r = t >> 4;
            int c4 = t & 15;
            float4 v = make_float4(0.f, 0.f, 0.f, 0.f);
            int gr = m0 + r;
            if (gr < M) v = *reinterpret_cast<const float4*>(&A[(size_t)gr * K + k0 + c4 * 4]);
            *reinterpret_cast<float4*>(&As[r * 64 + c4 * 4]) = v;
        }
        // stage B tile (64 x TN)
        for (int t = tid; t < 64 * TN / 4; t += 256) {
            int r = t / (TN / 4);
            int c4 = t % (TN / 4);
            float4 v = *reinterpret_cast<const float4*>(&W[(size_t)(k0 + r) * TN + c4 * 4]);
            *reinterpret_cast<float4*>(&Bs[r * TN + c4 * 4]) = v;
        }
        __syncthreads();
#pragma unroll 8
        for (int k = 0; k < 64; k++) {
            float b[NJ];
#pragma unroll
            for (int j = 0; j < NJ; j++) b[j] = Bs[k * TN + tx + 32 * j];
#pragma unroll
            for (int i = 0; i < 8; i++) {
                float a = As[(ty + 8 * i) * 64 + k];
#pragma unroll
                for (int j = 0; j < NJ; j++) acc[i][j] = fmaf(a, b[j], acc[i][j]);
            }
        }
        __syncthreads();
    }
#pragma unroll
    for (int i = 0; i < 8; i++) {
        int gr = m0 + ty + 8 * i;
        if (gr < M) {
#pragma unroll
            for (int j = 0; j < NJ; j++) {
                float v = acc[i][j] + bias[tx + 32 * j];
                if (RELU) v = fmaxf(v, 0.f);
                out[(size_t)gr * TN + tx + 32 * j] = v;
            }
        }
    }
}

// ---------------- launch ----------------

extern "C" void kernel_launch(void* const* d_in, const int* in_sizes, int n_in,
                              void* d_out, int out_size, void* d_ws, size_t ws_size,
                              hipStream_t stream) {
    const float* feat0 = (const float*)d_in[0];
    const float* feat1 = (const float*)d_in[1];
    const float* feat2 = (const float*)d_in[2];
    const float* W0 = (const float*)d_in[3];
    const float* b0 = (const float*)d_in[4];
    const float* W1 = (const float*)d_in[5];
    const float* b1 = (const float*)d_in[6];
    const float* W2 = (const float*)d_in[7];
    const float* b2 = (const float*)d_in[8];
    const float* bias_l0 = (const float*)d_in[9];
    const float* W_l1 = (const float*)d_in[10];
    const float* b_l1 = (const float*)d_in[11];
    const float* W_l2 = (const float*)d_in[12];
    const float* b_l2 = (const float*)d_in[13];
    const int* src = (const int*)d_in[14];
    const int* dst = (const int*)d_in[15];
    float* out = (float*)d_out;

    char* ws = (char*)d_ws;
    size_t off = 0;
    auto alloc = [&](size_t bytes) {
        size_t cur = off;
        off += (bytes + 255) & ~(size_t)255;
        return cur;
    };
    size_t hA_off = alloc((size_t)N_NODES * H_ * 4);
    size_t hB_off = alloc((size_t)N_NODES * H_ * 4);
    size_t ns_off = alloc((size_t)N_NODES * 4);
    size_t nd_off = alloc((size_t)N_NODES * 4);
    size_t counts_off = alloc((size_t)N_NODES * 4);
    size_t cursor_off = alloc((size_t)N_NODES * 4);
    size_t rowptr_off = alloc((size_t)(N_NODES + 1) * 4);
    size_t col_off = alloc((size_t)E_EDGES * 4);

    float* hA = (float*)(ws + hA_off);
    float* hB = (float*)(ws + hB_off);
    float* ns = (float*)(ws + ns_off);
    float* nd = (float*)(ws + nd_off);
    int* counts = (int*)(ws + counts_off);
    int* cursor = (int*)(ws + cursor_off);
    int* rowptr = (int*)(ws + rowptr_off);
    int* col = (int*)(ws + col_off);

    // zero ns/nd/counts/cursor (contiguous region)
    hipMemsetAsync(ws + ns_off, 0, rowptr_off - ns_off, stream);

    const int EB = (E_EDGES + 255) / 256;
    const int NB = (N_NODES + 255) / 256;

    deg_kernel<<<EB, 256, 0, stream>>>(src, dst, ns, nd, counts);
    scan_kernel<<<1, 256, 0, stream>>>(counts, rowptr);
    norm_kernel<<<NB, 256, 0, stream>>>(ns, nd);
    fill_kernel<<<EB, 256, 0, stream>>>(src, dst, rowptr, cursor, col);

    // per-type projections -> hA
    gemm_kernel<128, false><<<(N0_ + 63) / 64, 256, 0, stream>>>(feat0, W0, b0, hA, N0_, 512);
    gemm_kernel<128, false><<<(N1_ + 63) / 64, 256, 0, stream>>>(
        feat1, W1, b1, hA + (size_t)N0_ * H_, N1_, 256);
    gemm_kernel<128, false><<<(N2_ + 63) / 64, 256, 0, stream>>>(
        feat2, W2, b2, hA + (size_t)(N0_ + N1_) * H_, N2_, 128);

    // layer 0: agg + bias + relu
    agg_kernel<1><<<N_NODES, 128, 0, stream>>>(hA, rowptr, col, ns, nd, bias_l0, hB);
    // layer 1: agg then GEMM + relu
    agg_kernel<0><<<N_NODES, 128, 0, stream>>>(hB, rowptr, col, ns, nd, nullptr, hA);
    gemm_kernel<128, true><<<(N_NODES + 63) / 64, 256, 0, stream>>>(hA, W_l1, b_l1, hB, N_NODES, 128);
    // layer 2: agg then GEMM (no relu)
    agg_kernel<0><<<N_NODES, 128, 0, stream>>>(hB, rowptr, col, ns, nd, nullptr, hA);
    gemm_kernel<64, false><<<(N_NODES + 63) / 64, 256, 0, stream>>>(hA, W_l2, b_l2, out, N_NODES, 128);
}

// Round 2
// 641.616 us; speedup vs baseline: 1.1431x; 1.1431x over previous
//
#include <hip/hip_runtime.h>

#define N_NODES 50000
#define N0_ 20000
#define N1_ 15000
#define N2_ 15000
#define E_EDGES 800000
#define H_ 128
#define C_ 64

// ---------------- CSR build ----------------
// Pass 1: rank[e] = slot of edge e within its dst bucket; cnt[] ends as in-degree;
//         degO[] ends as out-degree. 2 atomics/edge (was 4 across deg+fill).

__global__ void rank_kernel(const int* __restrict__ src, const int* __restrict__ dst,
                            int* __restrict__ cnt, int* __restrict__ degO,
                            int* __restrict__ rank) {
    int i = blockIdx.x * 256 + threadIdx.x;
    if (i < E_EDGES) {
        rank[i] = atomicAdd(&cnt[dst[i]], 1);
        atomicAdd(&degO[src[i]], 1);
    }
}

__global__ void norm_kernel(const int* __restrict__ degO, const int* __restrict__ cnt,
                            float* __restrict__ ns, float* __restrict__ nd) {
    int i = blockIdx.x * 256 + threadIdx.x;
    if (i < N_NODES) {
        ns[i] = rsqrtf(fmaxf((float)degO[i], 1.0f));
        nd[i] = rsqrtf(fmaxf((float)cnt[i], 1.0f));
    }
}

__global__ void scan_kernel(const int* __restrict__ counts, int* __restrict__ rowptr) {
    __shared__ int sums[256];
    __shared__ int offs[257];
    int tid = threadIdx.x;
    const int chunk = (N_NODES + 255) / 256;
    int start = tid * chunk;
    int end = min(start + chunk, N_NODES);
    int s = 0;
    for (int i = start; i < end; i++) s += counts[i];
    sums[tid] = s;
    __syncthreads();
    if (tid == 0) {
        int acc = 0;
        for (int i = 0; i < 256; i++) { offs[i] = acc; acc += sums[i]; }
        offs[256] = acc;
    }
    __syncthreads();
    int acc = offs[tid];
    for (int i = start; i < end; i++) { rowptr[i] = acc; acc += counts[i]; }
    if (tid == 0) rowptr[N_NODES] = offs[256];
}

// Pass 2: pure scatter, no atomics.
__global__ void col_fill_kernel(const int* __restrict__ src, const int* __restrict__ dst,
                                const int* __restrict__ rowptr, const int* __restrict__ rank,
                                int* __restrict__ col) {
    int i = blockIdx.x * 256 + threadIdx.x;
    if (i < E_EDGES) {
        col[rowptr[dst[i]] + rank[i]] = src[i];
    }
}

// ---------------- aggregation ----------------
// 64-lane group per node; lane handles 2 channels via float2 (512B/wave/edge).
// out[node][c] = nd[node] * sum_e ns[src_e] * h[src_e][c]   (+ bias, relu for EPI==1)

template <int EPI>
__global__ __launch_bounds__(256) void agg_kernel(
    const float* __restrict__ h, const int* __restrict__ rowptr,
    const int* __restrict__ col, const float* __restrict__ ns,
    const float* __restrict__ nd, const float* __restrict__ bias,
    float* __restrict__ out) {
    int node = blockIdx.x * 4 + (threadIdx.x >> 6);
    if (node >= N_NODES) return;
    int lane = threadIdx.x & 63;
    const float2* __restrict__ h2 = (const float2*)h;
    int beg = rowptr[node], end = rowptr[node + 1];
    float2 acc = make_float2(0.f, 0.f);
    for (int e = beg; e < end; e++) {
        int s = col[e];
        float w = ns[s];
        float2 v = h2[(size_t)s * 64 + lane];
        acc.x = fmaf(w, v.x, acc.x);
        acc.y = fmaf(w, v.y, acc.y);
    }
    float w = nd[node];
    acc.x *= w;
    acc.y *= w;
    if (EPI == 1) {
        acc.x = fmaxf(acc.x + bias[2 * lane], 0.f);
        acc.y = fmaxf(acc.y + bias[2 * lane + 1], 0.f);
    }
    ((float2*)out)[(size_t)node * 64 + lane] = acc;
}

// ---------------- fp32 tiled GEMM: out[M,TN] = A[M,K] @ W[K,TN] + bias ----------------

template <int TN, bool RELU>
__global__ __launch_bounds__(256) void gemm_kernel(
    const float* __restrict__ A, const float* __restrict__ W,
    const float* __restrict__ bias, float* __restrict__ out, int M, int K) {
    constexpr int NJ = TN / 32;
    __shared__ float As[64 * 64];
    __shared__ float Bs[64 * TN];
    int tid = threadIdx.x;
    int tx = tid & 31;
    int ty = tid >> 5;
    int m0 = blockIdx.x * 64;

    float acc[8][NJ];
#pragma unroll
    for (int i = 0; i < 8; i++)
#pragma unroll
        for (int j = 0; j < NJ; j++) acc[i][j] = 0.f;

    for (int k0 = 0; k0 < K; k0 += 64) {
        for (int t = tid; t < 1024; t += 256) {
            int r = t >> 4;
            int c4 = t & 15;
            float4 v = make_float4(0.f, 0.f, 0.f, 0.f);
            int gr = m0 + r;
            if (gr < M) v = *reinterpret_cast<const float4*>(&A[(size_t)gr * K + k0 + c4 * 4]);
            *reinterpret_cast<float4*>(&As[r * 64 + c4 * 4]) = v;
        }
        for (int t = tid; t < 64 * TN / 4; t += 256) {
            int r = t / (TN / 4);
            int c4 = t % (TN / 4);
            float4 v = *reinterpret_cast<const float4*>(&W[(size_t)(k0 + r) * TN + c4 * 4]);
            *reinterpret_cast<float4*>(&Bs[r * TN + c4 * 4]) = v;
        }
        __syncthreads();
#pragma unroll 8
        for (int k = 0; k < 64; k++) {
            float b[NJ];
#pragma unroll
            for (int j = 0; j < NJ; j++) b[j] = Bs[k * TN + tx + 32 * j];
#pragma unroll
            for (int i = 0; i < 8; i++) {
                float a = As[(ty + 8 * i) * 64 + k];
#pragma unroll
                for (int j = 0; j < NJ; j++) acc[i][j] = fmaf(a, b[j], acc[i][j]);
            }
        }
        __syncthreads();
    }
#pragma unroll
    for (int i = 0; i < 8; i++) {
        int gr = m0 + ty + 8 * i;
        if (gr < M) {
#pragma unroll
            for (int j = 0; j < NJ; j++) {
                float v = acc[i][j] + bias[tx + 32 * j];
                if (RELU) v = fmaxf(v, 0.f);
                out[(size_t)gr * TN + tx + 32 * j] = v;
            }
        }
    }
}

// ---------------- launch ----------------

extern "C" void kernel_launch(void* const* d_in, const int* in_sizes, int n_in,
                              void* d_out, int out_size, void* d_ws, size_t ws_size,
                              hipStream_t stream) {
    const float* feat0 = (const float*)d_in[0];
    const float* feat1 = (const float*)d_in[1];
    const float* feat2 = (const float*)d_in[2];
    const float* W0 = (const float*)d_in[3];
    const float* b0 = (const float*)d_in[4];
    const float* W1 = (const float*)d_in[5];
    const float* b1 = (const float*)d_in[6];
    const float* W2 = (const float*)d_in[7];
    const float* b2 = (const float*)d_in[8];
    const float* bias_l0 = (const float*)d_in[9];
    const float* W_l1 = (const float*)d_in[10];
    const float* b_l1 = (const float*)d_in[11];
    const float* W_l2 = (const float*)d_in[12];
    const float* b_l2 = (const float*)d_in[13];
    const int* src = (const int*)d_in[14];
    const int* dst = (const int*)d_in[15];
    float* out = (float*)d_out;

    char* ws = (char*)d_ws;
    size_t off = 0;
    auto alloc = [&](size_t bytes) {
        size_t cur = off;
        off += (bytes + 255) & ~(size_t)255;
        return cur;
    };
    size_t hA_off = alloc((size_t)N_NODES * H_ * 4);
    size_t hB_off = alloc((size_t)N_NODES * H_ * 4);
    size_t cnt_off = alloc((size_t)N_NODES * 4);     // zeroed each call
    size_t degO_off = alloc((size_t)N_NODES * 4);    // zeroed each call
    size_t ns_off = alloc((size_t)N_NODES * 4);
    size_t nd_off = alloc((size_t)N_NODES * 4);
    size_t rowptr_off = alloc((size_t)(N_NODES + 1) * 4);
    size_t rank_off = alloc((size_t)E_EDGES * 4);
    size_t col_off = alloc((size_t)E_EDGES * 4);

    float* hA = (float*)(ws + hA_off);
    float* hB = (float*)(ws + hB_off);
    int* cnt = (int*)(ws + cnt_off);
    int* degO = (int*)(ws + degO_off);
    float* ns = (float*)(ws + ns_off);
    float* nd = (float*)(ws + nd_off);
    int* rowptr = (int*)(ws + rowptr_off);
    int* rank = (int*)(ws + rank_off);
    int* col = (int*)(ws + col_off);

    // zero cnt + degO (contiguous)
    hipMemsetAsync(ws + cnt_off, 0, ns_off - cnt_off, stream);

    const int EB = (E_EDGES + 255) / 256;
    const int NB = (N_NODES + 255) / 256;

    rank_kernel<<<EB, 256, 0, stream>>>(src, dst, cnt, degO, rank);
    scan_kernel<<<1, 256, 0, stream>>>(cnt, rowptr);
    norm_kernel<<<NB, 256, 0, stream>>>(degO, cnt, ns, nd);
    col_fill_kernel<<<EB, 256, 0, stream>>>(src, dst, rowptr, rank, col);

    // per-type projections -> hA
    gemm_kernel<128, false><<<(N0_ + 63) / 64, 256, 0, stream>>>(feat0, W0, b0, hA, N0_, 512);
    gemm_kernel<128, false><<<(N1_ + 63) / 64, 256, 0, stream>>>(
        feat1, W1, b1, hA + (size_t)N0_ * H_, N1_, 256);
    gemm_kernel<128, false><<<(N2_ + 63) / 64, 256, 0, stream>>>(
        feat2, W2, b2, hA + (size_t)(N0_ + N1_) * H_, N2_, 128);

    const int AGB = (N_NODES + 3) / 4;
    // layer 0: agg + bias + relu
    agg_kernel<1><<<AGB, 256, 0, stream>>>(hA, rowptr, col, ns, nd, bias_l0, hB);
    // layer 1: agg then GEMM + relu
    agg_kernel<0><<<AGB, 256, 0, stream>>>(hB, rowptr, col, ns, nd, nullptr, hA);
    gemm_kernel<128, true><<<(N_NODES + 63) / 64, 256, 0, stream>>>(hA, W_l1, b_l1, hB, N_NODES, 128);
    // layer 2: agg then GEMM (no relu)
    agg_kernel<0><<<AGB, 256, 0, stream>>>(hB, rowptr, col, ns, nd, nullptr, hA);
    gemm_kernel<64, false><<<(N_NODES + 63) / 64, 256, 0, stream>>>(hA, W_l2, b_l2, out, N_NODES, 128);
}

// Round 3
// 416.959 us; speedup vs baseline: 1.7590x; 1.5388x over previous
//
#include <hip/hip_runtime.h>

#define N_NODES 50000
#define N0_ 20000
#define N1_ 15000
#define N2_ 15000
#define E_EDGES 800000
#define H_ 128
#define C_ 64

#define PB0 ((N0_ + 63) / 64)              // 313
#define PB1 ((N1_ + 63) / 64)              // 235
#define PB2 ((N2_ + 63) / 64)              // 235
#define PB_TOTAL (PB0 + PB1 + PB2)         // 783
#define EB ((E_EDGES + 255) / 256)         // 3125
#define NB ((N_NODES + 255) / 256)         // 196

// ---------------- GEMM block: out[64, TN] tile = A[M,K] @ W[K,TN] ----------------
// A staged TRANSPOSED in LDS (As[k][row], stride 68 -> 16B-aligned b128 reads,
// ~2-way banks). Thread (tx,ty) owns rows ty*8..+7 (consecutive) x cols tx*NJ..+NJ-1
// (consecutive). Inner loop per k: 2x b128 (A) + 1x b128/b64 (B) + 8*NJ FMA.

template <int TN, bool RELU, bool SCALE>
__device__ __forceinline__ void gemm_block(
    const float* __restrict__ A, const float* __restrict__ W,
    const float* __restrict__ bias, const float* __restrict__ rowscale,
    float* __restrict__ out, int M, int K, int m0, float* As, float* Bs) {
    constexpr int NJ = TN / 32;
    constexpr int TN4 = TN / 4;
    int tid = threadIdx.x;
    int tx = tid & 31;
    int ty = tid >> 5;

    float acc[8][NJ];
#pragma unroll
    for (int i = 0; i < 8; i++)
#pragma unroll
        for (int j = 0; j < NJ; j++) acc[i][j] = 0.f;

    for (int k0 = 0; k0 < K; k0 += 32) {
        // stage A (64 rows x 32 k) transposed: As[k*68 + row]
#pragma unroll
        for (int t0 = 0; t0 < 2; t0++) {
            int t = tid + t0 * 256;
            int row = t >> 3;
            int c = t & 7;
            float4 v = make_float4(0.f, 0.f, 0.f, 0.f);
            if (m0 + row < M) v = *reinterpret_cast<const float4*>(&A[(size_t)(m0 + row) * K + k0 + c * 4]);
            As[(c * 4 + 0) * 68 + row] = v.x;
            As[(c * 4 + 1) * 68 + row] = v.y;
            As[(c * 4 + 2) * 68 + row] = v.z;
            As[(c * 4 + 3) * 68 + row] = v.w;
        }
        // stage B (32 x TN) row-major
#pragma unroll
        for (int t0 = 0; t0 < 32 * TN4 / 256; t0++) {
            int t = tid + t0 * 256;
            int r = t / TN4;
            int c4 = t % TN4;
            *reinterpret_cast<float4*>(&Bs[r * TN + c4 * 4]) =
                *reinterpret_cast<const float4*>(&W[(size_t)(k0 + r) * TN + c4 * 4]);
        }
        __syncthreads();
#pragma unroll 8
        for (int k = 0; k < 32; k++) {
            float4 a0 = *reinterpret_cast<float4*>(&As[k * 68 + ty * 8]);
            float4 a1 = *reinterpret_cast<float4*>(&As[k * 68 + ty * 8 + 4]);
            float ar[8] = {a0.x, a0.y, a0.z, a0.w, a1.x, a1.y, a1.z, a1.w};
            float br[NJ];
            if (NJ == 4) {
                float4 b = *reinterpret_cast<float4*>(&Bs[k * TN + tx * 4]);
                br[0] = b.x; br[1] = b.y; br[2] = b.z; br[3] = b.w;
            } else {
                float2 b = *reinterpret_cast<float2*>(&Bs[k * TN + tx * 2]);
                br[0] = b.x; br[1] = b.y;
            }
#pragma unroll
            for (int i = 0; i < 8; i++)
#pragma unroll
                for (int j = 0; j < NJ; j++) acc[i][j] = fmaf(ar[i], br[j], acc[i][j]);
        }
        __syncthreads();
    }
#pragma unroll
    for (int i = 0; i < 8; i++) {
        int row = m0 + ty * 8 + i;
        if (row < M) {
            float sc = SCALE ? rowscale[row] : 1.f;
            float v[NJ];
#pragma unroll
            for (int j = 0; j < NJ; j++) {
                v[j] = acc[i][j] + bias[tx * NJ + j];
                if (RELU) v[j] = fmaxf(v[j], 0.f);
                v[j] *= sc;
            }
            if (NJ == 4) {
                *reinterpret_cast<float4*>(&out[(size_t)row * TN + tx * 4]) =
                    make_float4(v[0], v[1], v[2], v[3]);
            } else {
                *reinterpret_cast<float2*>(&out[(size_t)row * TN + tx * 2]) =
                    make_float2(v[0], v[1]);
            }
        }
    }
}

// ---------------- K1: projections (3 segments) || rank (CSR pass 1) ----------------

__global__ __launch_bounds__(256) void k1_proj_rank(
    const float* __restrict__ feat0, const float* __restrict__ feat1, const float* __restrict__ feat2,
    const float* __restrict__ W0, const float* __restrict__ b0,
    const float* __restrict__ W1, const float* __restrict__ b1,
    const float* __restrict__ W2, const float* __restrict__ b2,
    float* __restrict__ hA,
    const int* __restrict__ src, const int* __restrict__ dst,
    int* __restrict__ cnt, int* __restrict__ degO, int* __restrict__ rank) {
    __shared__ float As[32 * 68];
    __shared__ float Bs[32 * 128];
    int bid = blockIdx.x;
    if (bid < PB_TOTAL) {
        const float* A; const float* Wp; const float* bp; float* op; int M, K, m0;
        if (bid < PB0) {
            A = feat0; Wp = W0; bp = b0; op = hA; M = N0_; K = 512; m0 = bid * 64;
        } else if (bid < PB0 + PB1) {
            A = feat1; Wp = W1; bp = b1; op = hA + (size_t)N0_ * H_; M = N1_; K = 256;
            m0 = (bid - PB0) * 64;
        } else {
            A = feat2; Wp = W2; bp = b2; op = hA + (size_t)(N0_ + N1_) * H_; M = N2_; K = 128;
            m0 = (bid - PB0 - PB1) * 64;
        }
        gemm_block<128, false, false>(A, Wp, bp, nullptr, op, M, K, m0, As, Bs);
    } else {
        int e = (bid - PB_TOTAL) * 256 + threadIdx.x;
        if (e < E_EDGES) {
            rank[e] = atomicAdd(&cnt[dst[e]], 1);
            atomicAdd(&degO[src[e]], 1);
        }
    }
}

// ---------------- scan (rowptr) ----------------

__global__ void scan_kernel(const int* __restrict__ counts, int* __restrict__ rowptr) {
    __shared__ int sums[256];
    __shared__ int offs[257];
    int tid = threadIdx.x;
    const int chunk = (N_NODES + 255) / 256;
    int start = tid * chunk;
    int end = min(start + chunk, N_NODES);
    int s = 0;
    for (int i = start; i < end; i++) s += counts[i];
    sums[tid] = s;
    __syncthreads();
    if (tid == 0) {
        int acc = 0;
        for (int i = 0; i < 256; i++) { offs[i] = acc; acc += sums[i]; }
        offs[256] = acc;
    }
    __syncthreads();
    int acc = offs[tid];
    for (int i = start; i < end; i++) { rowptr[i] = acc; acc += counts[i]; }
    if (tid == 0) rowptr[N_NODES] = offs[256];
}

// ---------------- K2: norm || col_fill (pure scatter) ----------------

__global__ __launch_bounds__(256) void k2_norm_fill(
    const int* __restrict__ degO, const int* __restrict__ cnt,
    float* __restrict__ ns, float* __restrict__ nd,
    const int* __restrict__ src, const int* __restrict__ dst,
    const int* __restrict__ rowptr, const int* __restrict__ rank,
    int* __restrict__ col) {
    int bid = blockIdx.x;
    if (bid < NB) {
        int i = bid * 256 + threadIdx.x;
        if (i < N_NODES) {
            ns[i] = rsqrtf(fmaxf((float)degO[i], 1.0f));
            nd[i] = rsqrtf(fmaxf((float)cnt[i], 1.0f));
        }
    } else {
        int e = (bid - NB) * 256 + threadIdx.x;
        if (e < E_EDGES) col[rowptr[dst[e]] + rank[e]] = src[e];
    }
}

// ---------------- aggregation ----------------
// 64-lane group per node, float2/lane. Unroll-4: 4 independent gather chains.
// NSLOAD: multiply by ns[src] per edge (layer 0 only; later layers have ns folded
// into the producer's epilogue). EPI=1: +bias, relu, then *ns[node] (fold for next).

template <int NSLOAD, int EPI>
__global__ __launch_bounds__(256) void agg_kernel(
    const float* __restrict__ h, const int* __restrict__ rowptr,
    const int* __restrict__ col, const float* __restrict__ ns,
    const float* __restrict__ nd, const float* __restrict__ bias,
    float* __restrict__ out) {
    int node = blockIdx.x * 4 + (threadIdx.x >> 6);
    if (node >= N_NODES) return;
    int lane = threadIdx.x & 63;
    const float2* __restrict__ h2 = (const float2*)h;
    int beg = rowptr[node], end = rowptr[node + 1];
    float2 a0 = make_float2(0.f, 0.f), a1 = a0, a2 = a0, a3 = a0;
    int e = beg;
    for (; e + 3 < end; e += 4) {
        int s0 = col[e], s1 = col[e + 1], s2 = col[e + 2], s3 = col[e + 3];
        float2 v0 = h2[(size_t)s0 * 64 + lane];
        float2 v1 = h2[(size_t)s1 * 64 + lane];
        float2 v2 = h2[(size_t)s2 * 64 + lane];
        float2 v3 = h2[(size_t)s3 * 64 + lane];
        if (NSLOAD) {
            float w0 = ns[s0], w1 = ns[s1], w2 = ns[s2], w3 = ns[s3];
            a0.x = fmaf(w0, v0.x, a0.x); a0.y = fmaf(w0, v0.y, a0.y);
            a1.x = fmaf(w1, v1.x, a1.x); a1.y = fmaf(w1, v1.y, a1.y);
            a2.x = fmaf(w2, v2.x, a2.x); a2.y = fmaf(w2, v2.y, a2.y);
            a3.x = fmaf(w3, v3.x, a3.x); a3.y = fmaf(w3, v3.y, a3.y);
        } else {
            a0.x += v0.x; a0.y += v0.y;
            a1.x += v1.x; a1.y += v1.y;
            a2.x += v2.x; a2.y += v2.y;
            a3.x += v3.x; a3.y += v3.y;
        }
    }
    for (; e < end; e++) {
        int s = col[e];
        float2 v = h2[(size_t)s * 64 + lane];
        if (NSLOAD) {
            float w = ns[s];
            a0.x = fmaf(w, v.x, a0.x); a0.y = fmaf(w, v.y, a0.y);
        } else {
            a0.x += v.x; a0.y += v.y;
        }
    }
    float2 acc = make_float2((a0.x + a1.x) + (a2.x + a3.x), (a0.y + a1.y) + (a2.y + a3.y));
    float w = nd[node];
    acc.x *= w; acc.y *= w;
    if (EPI == 1) {
        float sc = ns[node];
        acc.x = fmaxf(acc.x + bias[2 * lane], 0.f) * sc;
        acc.y = fmaxf(acc.y + bias[2 * lane + 1], 0.f) * sc;
    }
    ((float2*)out)[(size_t)node * 64 + lane] = acc;
}

// ---------------- standalone GEMM (layers 1/2) ----------------

template <int TN, bool RELU, bool SCALE>
__global__ __launch_bounds__(256) void gemm_kernel(
    const float* __restrict__ A, const float* __restrict__ W,
    const float* __restrict__ bias, const float* __restrict__ rowscale,
    float* __restrict__ out, int M, int K) {
    __shared__ float As[32 * 68];
    __shared__ float Bs[32 * TN];
    gemm_block<TN, RELU, SCALE>(A, W, bias, rowscale, out, M, K, blockIdx.x * 64, As, Bs);
}

// ---------------- launch ----------------

extern "C" void kernel_launch(void* const* d_in, const int* in_sizes, int n_in,
                              void* d_out, int out_size, void* d_ws, size_t ws_size,
                              hipStream_t stream) {
    const float* feat0 = (const float*)d_in[0];
    const float* feat1 = (const float*)d_in[1];
    const float* feat2 = (const float*)d_in[2];
    const float* W0 = (const float*)d_in[3];
    const float* b0 = (const float*)d_in[4];
    const float* W1 = (const float*)d_in[5];
    const float* b1 = (const float*)d_in[6];
    const float* W2 = (const float*)d_in[7];
    const float* b2 = (const float*)d_in[8];
    const float* bias_l0 = (const float*)d_in[9];
    const float* W_l1 = (const float*)d_in[10];
    const float* b_l1 = (const float*)d_in[11];
    const float* W_l2 = (const float*)d_in[12];
    const float* b_l2 = (const float*)d_in[13];
    const int* src = (const int*)d_in[14];
    const int* dst = (const int*)d_in[15];
    float* out = (float*)d_out;

    char* ws = (char*)d_ws;
    size_t off = 0;
    auto alloc = [&](size_t bytes) {
        size_t cur = off;
        off += (bytes + 255) & ~(size_t)255;
        return cur;
    };
    size_t hA_off = alloc((size_t)N_NODES * H_ * 4);
    size_t hB_off = alloc((size_t)N_NODES * H_ * 4);
    size_t cnt_off = alloc((size_t)N_NODES * 4);   // zeroed each call
    size_t degO_off = alloc((size_t)N_NODES * 4);  // zeroed each call
    size_t ns_off = alloc((size_t)N_NODES * 4);
    size_t nd_off = alloc((size_t)N_NODES * 4);
    size_t rowptr_off = alloc((size_t)(N_NODES + 1) * 4);
    size_t rank_off = alloc((size_t)E_EDGES * 4);
    size_t col_off = alloc((size_t)E_EDGES * 4);

    float* hA = (float*)(ws + hA_off);
    float* hB = (float*)(ws + hB_off);
    int* cnt = (int*)(ws + cnt_off);
    int* degO = (int*)(ws + degO_off);
    float* ns = (float*)(ws + ns_off);
    float* nd = (float*)(ws + nd_off);
    int* rowptr = (int*)(ws + rowptr_off);
    int* rank = (int*)(ws + rank_off);
    int* col = (int*)(ws + col_off);

    hipMemsetAsync(ws + cnt_off, 0, ns_off - cnt_off, stream);

    // K1: projections || rank
    k1_proj_rank<<<PB_TOTAL + EB, 256, 0, stream>>>(
        feat0, feat1, feat2, W0, b0, W1, b1, W2, b2, hA, src, dst, cnt, degO, rank);
    scan_kernel<<<1, 256, 0, stream>>>(cnt, rowptr);
    // K2: norm || col_fill
    k2_norm_fill<<<NB + EB, 256, 0, stream>>>(degO, cnt, ns, nd, src, dst, rowptr, rank, col);

    const int AGB = (N_NODES + 3) / 4;
    // layer 0: agg(ns-weighted) + bias + relu, output pre-scaled by ns
    agg_kernel<1, 1><<<AGB, 256, 0, stream>>>(hA, rowptr, col, ns, nd, bias_l0, hB);
    // layer 1: agg (input pre-scaled), then GEMM + relu, output pre-scaled by ns
    agg_kernel<0, 0><<<AGB, 256, 0, stream>>>(hB, rowptr, col, ns, nd, nullptr, hA);
    gemm_kernel<128, true, true><<<(N_NODES + 63) / 64, 256, 0, stream>>>(
        hA, W_l1, b_l1, ns, hB, N_NODES, 128);
    // layer 2: agg (input pre-scaled), then GEMM (no relu, no scale)
    agg_kernel<0, 0><<<AGB, 256, 0, stream>>>(hB, rowptr, col, ns, nd, nullptr, hA);
    gemm_kernel<64, false, false><<<(N_NODES + 63) / 64, 256, 0, stream>>>(
        hA, W_l2, b_l2, nullptr, out, N_NODES, 128);
}